// Round 8
// baseline (140.537 us; speedup 1.0000x reference)
//
#include <hip/hip_runtime.h>
#include <math.h>

#define Dm 256
#define Tt 4096

typedef short  s16x8 __attribute__((ext_vector_type(8)));
typedef float  f32x4 __attribute__((ext_vector_type(4)));

__device__ __forceinline__ ushort f2bf(float x) {
    union { float f; unsigned u; } v; v.f = x;
    unsigned r = v.u + 0x7fffu + ((v.u >> 16) & 1u);   // RNE
    return (ushort)(r >> 16);
}

// P_s position: row-major [16][64] ushort with block-XOR swizzle (f(row)=row>>1)
__device__ __forceinline__ int ppos(int row, int key) {
    return row * 64 + (key & 7) + ((((key >> 3) ^ (row >> 1)) & 7) << 3);
}

// ---------------- convert: x(+pos) fp32 -> bf16, 3 matrices ----------------
// grid (128, 3), block 256. token tile of 32, each thread 32 consecutive cols.
__global__ __launch_bounds__(256)
void convert_x(const float* __restrict__ xq, const float* __restrict__ xkv,
               const float* __restrict__ pos,
               ushort* __restrict__ A0, ushort* __restrict__ A1, ushort* __restrict__ A2)
{
    const int t = threadIdx.x;
    const int m = blockIdx.y;
    const float* xin = (m == 0) ? xq : xkv;
    ushort* out = (m == 0) ? A0 : (m == 1) ? A1 : A2;
    const int token = blockIdx.x * 32 + (t >> 3);
    const int c0 = (t & 7) * 32;
    const float* p = &xin[token * Dm + c0];
    const float* pp = &pos[token * Dm + c0];
    #pragma unroll
    for (int i = 0; i < 4; ++i) {
        float4 fa = *(const float4*)&p[i * 8];
        float4 fb = *(const float4*)&p[i * 8 + 4];
        if (m < 2) {
            float4 pa = *(const float4*)&pp[i * 8], pb = *(const float4*)&pp[i * 8 + 4];
            fa.x += pa.x; fa.y += pa.y; fa.z += pa.z; fa.w += pa.w;
            fb.x += pb.x; fb.y += pb.y; fb.z += pb.z; fb.w += pb.w;
        }
        s16x8 v8;
        v8[0] = (short)f2bf(fa.x); v8[1] = (short)f2bf(fa.y);
        v8[2] = (short)f2bf(fa.z); v8[3] = (short)f2bf(fa.w);
        v8[4] = (short)f2bf(fb.x); v8[5] = (short)f2bf(fb.y);
        v8[6] = (short)f2bf(fb.z); v8[7] = (short)f2bf(fb.w);
        *(s16x8*)&out[token * Dm + c0 + i * 8] = v8;
    }
}

// ---------------- prep: W[k][c] fp32 -> Wt[c][k] bf16, 4 matrices ----------------
__global__ __launch_bounds__(256)
void prep_w(const float* __restrict__ Wq, const float* __restrict__ Wk,
            const float* __restrict__ Wv, const float* __restrict__ Wo,
            ushort* __restrict__ Wt)
{
    __shared__ float T[64][65];
    const int tid = threadIdx.x;
    const int m = blockIdx.y;
    const int i = blockIdx.x >> 2, j = blockIdx.x & 3;
    const float* W = (m == 0) ? Wq : (m == 1) ? Wk : (m == 2) ? Wv : Wo;

    #pragma unroll
    for (int s = 0; s < 4; ++s) {
        int idx = s * 256 + tid;
        int r = idx >> 4, c4 = (idx & 15) << 2;
        float4 f = *(const float4*)&W[(i * 64 + r) * Dm + j * 64 + c4];
        T[c4 + 0][r] = f.x; T[c4 + 1][r] = f.y;
        T[c4 + 2][r] = f.z; T[c4 + 3][r] = f.w;
    }
    __syncthreads();
    #pragma unroll
    for (int s = 0; s < 2; ++s) {
        int idx = s * 256 + tid;
        int cr = idx >> 3, k8 = (idx & 7) << 3;
        s16x8 v8;
        #pragma unroll
        for (int jj = 0; jj < 8; ++jj) v8[jj] = (short)f2bf(T[cr][k8 + jj]);
        *(s16x8*)&Wt[m * 65536 + (j * 64 + cr) * Dm + i * 64 + k8] = v8;
    }
}

// ---------------- QKV projection GEMM (bf16 in, bf16 out; v transposed) ----------------
// grid (64, 4, 3), block 256.
__global__ __launch_bounds__(256)
void proj_gemm(const ushort* __restrict__ A0, const ushort* __restrict__ A1,
               const ushort* __restrict__ A2, const ushort* __restrict__ Wt,
               const float* __restrict__ bq, const float* __restrict__ bk,
               const float* __restrict__ bv,
               ushort* __restrict__ qo, ushort* __restrict__ ko, ushort* __restrict__ vT)
{
    __shared__ __align__(16) ushort A_s[64 * 64];
    __shared__ __align__(16) ushort B_s[64 * 64];
    const int tid = threadIdx.x;
    const int lane = tid & 63, g = lane >> 4, myrow = lane & 15, w = tid >> 6;
    const int t0 = blockIdx.x * 64;
    const int c0 = blockIdx.y * 64;
    const int m  = blockIdx.z;
    const ushort* Ab = (m == 0) ? A0 : (m == 1) ? A1 : A2;
    const ushort* WT = Wt + m * 65536;
    const float* bias = (m == 0) ? bq : (m == 1) ? bk : bv;

    f32x4 acc[4] = {};
    for (int ks = 0; ks < 4; ++ks) {
        const int k0 = ks * 64;
        #pragma unroll
        for (int s = 0; s < 2; ++s) {
            int idx = s * 256 + tid;
            int r = idx >> 3, c = idx & 7;
            *(s16x8*)&A_s[r * 64 + ((c ^ (r & 7)) << 3)] =
                *(const s16x8*)&Ab[(t0 + r) * Dm + k0 + c * 8];
            *(s16x8*)&B_s[r * 64 + ((c ^ (r & 7)) << 3)] =
                *(const s16x8*)&WT[(c0 + r) * Dm + k0 + c * 8];
        }
        __syncthreads();
        const int arow = w * 16 + myrow;
        #pragma unroll
        for (int kk = 0; kk < 2; ++kk) {
            s16x8 a = *(s16x8*)&A_s[arow * 64 + (((g + 4 * kk) ^ (arow & 7)) << 3)];
            #pragma unroll
            for (int ct = 0; ct < 4; ++ct) {
                int brow = ct * 16 + myrow;
                s16x8 b = *(s16x8*)&B_s[brow * 64 + (((g + 4 * kk) ^ (brow & 7)) << 3)];
                acc[ct] = __builtin_amdgcn_mfma_f32_16x16x32_bf16(a, b, acc[ct], 0, 0, 0);
            }
        }
        __syncthreads();
    }
    const float qsc = 0.17677669529663687f;   // 1/sqrt(32) folded into q
    #pragma unroll
    for (int ct = 0; ct < 4; ++ct) {
        int col = c0 + ct * 16 + myrow;
        float bval = bias[col];
        #pragma unroll
        for (int r = 0; r < 4; ++r) {
            int tok = t0 + w * 16 + 4 * g + r;
            float vv = acc[ct][r] + bval;
            if (m == 0)      qo[tok * Dm + col] = f2bf(vv * qsc);
            else if (m == 1) ko[tok * Dm + col] = f2bf(vv);
            else             vT[col * Tt + tok] = f2bf(vv);
        }
    }
}

// ---------------- flash attention: 32 q-rows/block, 4 waves split K ----------------
// grid 1024 (128 q-tiles x 8 heads), block 256. No barriers in main loop.
__global__ __launch_bounds__(256)
void attn2(const ushort* __restrict__ q, const ushort* __restrict__ kb,
           const ushort* __restrict__ vT, ushort* __restrict__ o)
{
    __shared__ __align__(16) ushort K_s[4][64 * 32];   // per-wave [key][dh] linear
    __shared__ __align__(16) ushort V_s[4][32 * 64];   // per-wave [dh][key-blk^XOR]
    __shared__ __align__(16) ushort P_s[4][16 * 64];   // per-wave swizzled P
    const int tid = threadIdx.x;
    const int lane = tid & 63, g = lane >> 4, myrow = lane & 15, w = tid >> 6;
    const int h = blockIdx.x & 7, qt = blockIdx.x >> 3;

    int off, L;
    if (qt < 32)      { off = 0;    L = 1024; }
    else if (qt < 48) { off = 1024; L = 512;  }
    else if (qt < 96) { off = 1536; L = 1536; }
    else              { off = 3072; L = 1024; }
    const int qrow0 = qt * 32;
    const int Lw = L >> 2;
    const int kbeg = off + w * Lw;
    const int nt = Lw >> 6;

    s16x8 qf[2];
    qf[0] = *(const s16x8*)&q[(qrow0 + myrow) * Dm + h * 32 + g * 8];
    qf[1] = *(const s16x8*)&q[(qrow0 + 16 + myrow) * Dm + h * 32 + g * 8];

    f32x4 aO[2][2] = {};
    float mr[2][4], lr[2][4];
    #pragma unroll
    for (int s = 0; s < 2; ++s)
        #pragma unroll
        for (int r = 0; r < 4; ++r) { mr[s][r] = -INFINITY; lr[s][r] = 0.f; }

    s16x8 kr[4], vr[4];
    #define LOAD_TILE(kc) do {                                                          \
        int kcc = (kc);                                                                 \
        _Pragma("unroll")                                                               \
        for (int i = 0; i < 4; ++i) {                                                   \
            int idx = i * 64 + lane;                                                    \
            kr[i] = *(const s16x8*)&kb[(kcc + (idx >> 2)) * Dm + h * 32 + ((idx & 3) << 3)]; \
            vr[i] = *(const s16x8*)&vT[(h * 32 + (lane >> 3) + i * 8) * Tt + kcc + ((lane & 7) << 3)]; \
        }                                                                               \
    } while (0)

    LOAD_TILE(kbeg);
    for (int t = 0; t < nt; ++t) {
        // wait: prefetch arrived (vmcnt) + prior tile's LDS reads done (WAR, lgkm)
        asm volatile("s_waitcnt vmcnt(0) lgkmcnt(0)" ::: "memory");
        __builtin_amdgcn_sched_barrier(0);
        #pragma unroll
        for (int i = 0; i < 4; ++i) {
            int idx = i * 64 + lane;
            *(s16x8*)&K_s[w][(idx >> 2) * 32 + ((idx & 3) << 3)] = kr[i];
            int dh = (lane >> 3) + i * 8;
            *(s16x8*)&V_s[w][dh * 64 + (((lane & 7) ^ (dh & 7)) << 3)] = vr[i];
        }
        if (t + 1 < nt) LOAD_TILE(kbeg + (t + 1) * 64);     // T14: issue early
        asm volatile("s_waitcnt lgkmcnt(0)" ::: "memory");  // LDS writes visible (wave-local)
        __builtin_amdgcn_sched_barrier(0);

        #pragma unroll
        for (int s = 0; s < 2; ++s) {
            const f32x4 zero = {};
            f32x4 s4[4];
            #pragma unroll
            for (int kt = 0; kt < 4; ++kt) {
                s16x8 bkf = *(const s16x8*)&K_s[w][(kt * 16 + myrow) * 32 + g * 8];
                s4[kt] = __builtin_amdgcn_mfma_f32_16x16x32_bf16(qf[s], bkf, zero, 0, 0, 0);
            }
            float mt[4], sc[4], ps[4];
            #pragma unroll
            for (int r = 0; r < 4; ++r) {
                float a = fmaxf(fmaxf(s4[0][r], s4[1][r]), fmaxf(s4[2][r], s4[3][r]));
                a = fmaxf(a, __shfl_xor(a, 1));
                a = fmaxf(a, __shfl_xor(a, 2));
                a = fmaxf(a, __shfl_xor(a, 4));
                a = fmaxf(a, __shfl_xor(a, 8));
                mt[r] = a;
            }
            #pragma unroll
            for (int r = 0; r < 4; ++r) {
                float mn = fmaxf(mr[s][r], mt[r]);
                sc[r] = __expf(mr[s][r] - mn);
                mr[s][r] = mn;
                ps[r] = 0.f;
            }
            // WAR: previous PV's P_s reads must drain before overwrite
            asm volatile("s_waitcnt lgkmcnt(0)" ::: "memory");
            __builtin_amdgcn_sched_barrier(0);
            #pragma unroll
            for (int kt = 0; kt < 4; ++kt) {
                #pragma unroll
                for (int r = 0; r < 4; ++r) {
                    float p = __expf(s4[kt][r] - mr[s][r]);
                    ps[r] += p;
                    P_s[w][ppos(4 * g + r, 16 * kt + myrow)] = f2bf(p);
                }
            }
            #pragma unroll
            for (int r = 0; r < 4; ++r) {
                float sps = ps[r];
                sps += __shfl_xor(sps, 1);
                sps += __shfl_xor(sps, 2);
                sps += __shfl_xor(sps, 4);
                sps += __shfl_xor(sps, 8);
                lr[s][r] = lr[s][r] * sc[r] + sps;
                aO[s][0][r] *= sc[r];
                aO[s][1][r] *= sc[r];
            }
            asm volatile("s_waitcnt lgkmcnt(0)" ::: "memory");  // P writes visible
            __builtin_amdgcn_sched_barrier(0);
            #pragma unroll
            for (int kk = 0; kk < 2; ++kk) {
                s16x8 ap = *(const s16x8*)&P_s[w][ppos(myrow, (g + 4 * kk) * 8)];
                s16x8 b0 = *(const s16x8*)&V_s[w][myrow * 64 + (((4 * kk + g) ^ (myrow & 7)) << 3)];
                s16x8 b1 = *(const s16x8*)&V_s[w][(16 + myrow) * 64 + (((4 * kk + g) ^ (myrow & 7)) << 3)];
                aO[s][0] = __builtin_amdgcn_mfma_f32_16x16x32_bf16(ap, b0, aO[s][0], 0, 0, 0);
                aO[s][1] = __builtin_amdgcn_mfma_f32_16x16x32_bf16(ap, b1, aO[s][1], 0, 0, 0);
            }
        }
    }
    #undef LOAD_TILE

    // cross-wave combine: waves 1-3 publish partials, wave 0 merges + writes.
    __syncthreads();
    float* cmb = (float*)&K_s[0][0];    // [96 rows][36]: 32 O + m + l (13.8 KB)
    if (w > 0) {
        #pragma unroll
        for (int s = 0; s < 2; ++s)
            #pragma unroll
            for (int r = 0; r < 4; ++r) {
                int row = (w - 1) * 32 + s * 16 + 4 * g + r;
                cmb[row * 36 + myrow]      = aO[s][0][r];
                cmb[row * 36 + 16 + myrow] = aO[s][1][r];
                if (myrow == 0) { cmb[row * 36 + 32] = mr[s][r]; cmb[row * 36 + 33] = lr[s][r]; }
            }
    }
    __syncthreads();
    if (w == 0) {
        #pragma unroll
        for (int s = 0; s < 2; ++s) {
            #pragma unroll
            for (int r = 0; r < 4; ++r) {
                #pragma unroll
                for (int ww = 0; ww < 3; ++ww) {
                    int row = ww * 32 + s * 16 + 4 * g + r;
                    float m2 = cmb[row * 36 + 32], l2 = cmb[row * 36 + 33];
                    float mn = fmaxf(mr[s][r], m2);
                    float a1 = __expf(mr[s][r] - mn), a2 = __expf(m2 - mn);
                    mr[s][r] = mn;
                    lr[s][r] = lr[s][r] * a1 + l2 * a2;
                    aO[s][0][r] = aO[s][0][r] * a1 + cmb[row * 36 + myrow] * a2;
                    aO[s][1][r] = aO[s][1][r] * a1 + cmb[row * 36 + 16 + myrow] * a2;
                }
                float inv = 1.0f / lr[s][r];
                int orow = (qrow0 + s * 16 + 4 * g + r) * Dm + h * 32;
                o[orow + myrow]      = f2bf(aO[s][0][r] * inv);
                o[orow + 16 + myrow] = f2bf(aO[s][1][r] * inv);
            }
        }
    }
}

// ---------------- output projection ----------------
// grid (128, 4), block 256: 32-token x 64-col tiles; wave: (w>>1)=row-half, (w&1)=col-half.
__global__ __launch_bounds__(256)
void oproj_mfma(const ushort* __restrict__ A, const ushort* __restrict__ Wt3,
                const float* __restrict__ bo, float* __restrict__ out)
{
    __shared__ __align__(16) ushort A_s[32 * 64];
    __shared__ __align__(16) ushort B_s[64 * 64];
    const int tid = threadIdx.x;
    const int lane = tid & 63, g = lane >> 4, myrow = lane & 15, w = tid >> 6;
    const int sh = w >> 1, ch = w & 1;
    const int t0 = blockIdx.x * 32;
    const int c0 = blockIdx.y * 64;

    f32x4 acc[2] = {};
    for (int ks = 0; ks < 4; ++ks) {
        const int k0 = ks * 64;
        {
            int r = tid >> 3, c = tid & 7;
            *(s16x8*)&A_s[r * 64 + ((c ^ (r & 7)) << 3)] =
                *(const s16x8*)&A[(t0 + r) * Dm + k0 + c * 8];
        }
        #pragma unroll
        for (int s = 0; s < 2; ++s) {
            int idx = s * 256 + tid;
            int r = idx >> 3, c = idx & 7;
            *(s16x8*)&B_s[r * 64 + ((c ^ (r & 7)) << 3)] =
                *(const s16x8*)&Wt3[(c0 + r) * Dm + k0 + c * 8];
        }
        __syncthreads();
        const int arow = sh * 16 + myrow;
        #pragma unroll
        for (int kk = 0; kk < 2; ++kk) {
            s16x8 a = *(s16x8*)&A_s[arow * 64 + (((g + 4 * kk) ^ (arow & 7)) << 3)];
            #pragma unroll
            for (int ct = 0; ct < 2; ++ct) {
                int brow = ch * 32 + ct * 16 + myrow;
                s16x8 b = *(s16x8*)&B_s[brow * 64 + (((g + 4 * kk) ^ (brow & 7)) << 3)];
                acc[ct] = __builtin_amdgcn_mfma_f32_16x16x32_bf16(a, b, acc[ct], 0, 0, 0);
            }
        }
        __syncthreads();
    }
    #pragma unroll
    for (int ct = 0; ct < 2; ++ct) {
        int col = c0 + ch * 32 + ct * 16 + myrow;
        float bval = bo[col];
        #pragma unroll
        for (int r = 0; r < 4; ++r)
            out[(t0 + sh * 16 + 4 * g + r) * Dm + col] = acc[ct][r] + bval;
    }
}

extern "C" void kernel_launch(void* const* d_in, const int* in_sizes, int n_in,
                              void* d_out, int out_size, void* d_ws, size_t ws_size,
                              hipStream_t stream) {
    const float* xq  = (const float*)d_in[0];
    const float* xkv = (const float*)d_in[1];
    const float* pos = (const float*)d_in[2];
    const float* Wq  = (const float*)d_in[5];
    const float* bq  = (const float*)d_in[6];
    const float* Wk  = (const float*)d_in[7];
    const float* bk  = (const float*)d_in[8];
    const float* Wv  = (const float*)d_in[9];
    const float* bv  = (const float*)d_in[10];
    const float* Wo  = (const float*)d_in[11];
    const float* bo  = (const float*)d_in[12];

    ushort* Abf = (ushort*)d_ws;           // 3 x [T,D] bf16 (xq+pos, xkv+pos, xkv)
    ushort* qb  = Abf + 3 * Tt * Dm;       // [T,D]
    ushort* kbp = qb + Tt * Dm;            // [T,D]
    ushort* vT  = kbp + Tt * Dm;           // [D,T] transposed
    ushort* ab  = vT + Tt * Dm;            // attn out [T,D]
    ushort* Wt  = ab + Tt * Dm;            // 4 x [256,256] transposed bf16

    convert_x<<<dim3(Tt / 32, 3), 256, 0, stream>>>(xq, xkv, pos, Abf,
                                                    Abf + Tt * Dm, Abf + 2 * Tt * Dm);
    prep_w<<<dim3(16, 4), 256, 0, stream>>>(Wq, Wk, Wv, Wo, Wt);
    proj_gemm<<<dim3(64, 4, 3), 256, 0, stream>>>(Abf, Abf + Tt * Dm, Abf + 2 * Tt * Dm,
                                                  Wt, bq, bk, bv, qb, kbp, vT);
    attn2<<<dim3(1024), 256, 0, stream>>>(qb, kbp, vT, ab);
    oproj_mfma<<<dim3(128, 4), 256, 0, stream>>>(ab, Wt + 3 * 65536, bo, (float*)d_out);
}

// Round 9
// 135.147 us; speedup vs baseline: 1.0399x; 1.0399x over previous
//
#include <hip/hip_runtime.h>
#include <math.h>

#define Dm 256
#define Tt 4096

typedef short  s16x8 __attribute__((ext_vector_type(8)));
typedef float  f32x4 __attribute__((ext_vector_type(4)));

__device__ __forceinline__ ushort f2bf(float x) {
    union { float f; unsigned u; } v; v.f = x;
    unsigned r = v.u + 0x7fffu + ((v.u >> 16) & 1u);   // RNE
    return (ushort)(r >> 16);
}

// P_s position: row-major [16][64] ushort with block-XOR swizzle (f(row)=row>>1)
__device__ __forceinline__ int ppos(int row, int key) {
    return row * 64 + (key & 7) + ((((key >> 3) ^ (row >> 1)) & 7) << 3);
}

// ---------------- convert: x(+pos) fp32 -> bf16, 3 matrices ----------------
__global__ __launch_bounds__(256)
void convert_x(const float* __restrict__ xq, const float* __restrict__ xkv,
               const float* __restrict__ pos,
               ushort* __restrict__ A0, ushort* __restrict__ A1, ushort* __restrict__ A2)
{
    const int t = threadIdx.x;
    const int m = blockIdx.y;
    const float* xin = (m == 0) ? xq : xkv;
    ushort* out = (m == 0) ? A0 : (m == 1) ? A1 : A2;
    const int token = blockIdx.x * 32 + (t >> 3);
    const int c0 = (t & 7) * 32;
    const float* p = &xin[token * Dm + c0];
    const float* pp = &pos[token * Dm + c0];
    #pragma unroll
    for (int i = 0; i < 4; ++i) {
        float4 fa = *(const float4*)&p[i * 8];
        float4 fb = *(const float4*)&p[i * 8 + 4];
        if (m < 2) {
            float4 pa = *(const float4*)&pp[i * 8], pb = *(const float4*)&pp[i * 8 + 4];
            fa.x += pa.x; fa.y += pa.y; fa.z += pa.z; fa.w += pa.w;
            fb.x += pb.x; fb.y += pb.y; fb.z += pb.z; fb.w += pb.w;
        }
        s16x8 v8;
        v8[0] = (short)f2bf(fa.x); v8[1] = (short)f2bf(fa.y);
        v8[2] = (short)f2bf(fa.z); v8[3] = (short)f2bf(fa.w);
        v8[4] = (short)f2bf(fb.x); v8[5] = (short)f2bf(fb.y);
        v8[6] = (short)f2bf(fb.z); v8[7] = (short)f2bf(fb.w);
        *(s16x8*)&out[token * Dm + c0 + i * 8] = v8;
    }
}

// ---------------- prep: W[k][c] fp32 -> Wt[c][k] bf16, 4 matrices ----------------
__global__ __launch_bounds__(256)
void prep_w(const float* __restrict__ Wq, const float* __restrict__ Wk,
            const float* __restrict__ Wv, const float* __restrict__ Wo,
            ushort* __restrict__ Wt)
{
    __shared__ float T[64][65];
    const int tid = threadIdx.x;
    const int m = blockIdx.y;
    const int i = blockIdx.x >> 2, j = blockIdx.x & 3;
    const float* W = (m == 0) ? Wq : (m == 1) ? Wk : (m == 2) ? Wv : Wo;

    #pragma unroll
    for (int s = 0; s < 4; ++s) {
        int idx = s * 256 + tid;
        int r = idx >> 4, c4 = (idx & 15) << 2;
        float4 f = *(const float4*)&W[(i * 64 + r) * Dm + j * 64 + c4];
        T[c4 + 0][r] = f.x; T[c4 + 1][r] = f.y;
        T[c4 + 2][r] = f.z; T[c4 + 3][r] = f.w;
    }
    __syncthreads();
    #pragma unroll
    for (int s = 0; s < 2; ++s) {
        int idx = s * 256 + tid;
        int cr = idx >> 3, k8 = (idx & 7) << 3;
        s16x8 v8;
        #pragma unroll
        for (int jj = 0; jj < 8; ++jj) v8[jj] = (short)f2bf(T[cr][k8 + jj]);
        *(s16x8*)&Wt[m * 65536 + (j * 64 + cr) * Dm + i * 64 + k8] = v8;
    }
}

// ---------------- QKV projection GEMM (bf16 in, bf16 out, all row-major) ----------------
__global__ __launch_bounds__(256)
void proj_gemm(const ushort* __restrict__ A0, const ushort* __restrict__ A1,
               const ushort* __restrict__ A2, const ushort* __restrict__ Wt,
               const float* __restrict__ bq, const float* __restrict__ bk,
               const float* __restrict__ bv,
               ushort* __restrict__ qo, ushort* __restrict__ ko, ushort* __restrict__ vo)
{
    __shared__ __align__(16) ushort A_s[64 * 64];
    __shared__ __align__(16) ushort B_s[64 * 64];
    const int tid = threadIdx.x;
    const int lane = tid & 63, g = lane >> 4, myrow = lane & 15, w = tid >> 6;
    const int t0 = blockIdx.x * 64;
    const int c0 = blockIdx.y * 64;
    const int m  = blockIdx.z;
    const ushort* Ab = (m == 0) ? A0 : (m == 1) ? A1 : A2;
    const ushort* WT = Wt + m * 65536;
    const float* bias = (m == 0) ? bq : (m == 1) ? bk : bv;
    ushort* out = (m == 0) ? qo : (m == 1) ? ko : vo;

    f32x4 acc[4] = {};
    for (int ks = 0; ks < 4; ++ks) {
        const int k0 = ks * 64;
        #pragma unroll
        for (int s = 0; s < 2; ++s) {
            int idx = s * 256 + tid;
            int r = idx >> 3, c = idx & 7;
            *(s16x8*)&A_s[r * 64 + ((c ^ (r & 7)) << 3)] =
                *(const s16x8*)&Ab[(t0 + r) * Dm + k0 + c * 8];
            *(s16x8*)&B_s[r * 64 + ((c ^ (r & 7)) << 3)] =
                *(const s16x8*)&WT[(c0 + r) * Dm + k0 + c * 8];
        }
        __syncthreads();
        const int arow = w * 16 + myrow;
        #pragma unroll
        for (int kk = 0; kk < 2; ++kk) {
            s16x8 a = *(s16x8*)&A_s[arow * 64 + (((g + 4 * kk) ^ (arow & 7)) << 3)];
            #pragma unroll
            for (int ct = 0; ct < 4; ++ct) {
                int brow = ct * 16 + myrow;
                s16x8 b = *(s16x8*)&B_s[brow * 64 + (((g + 4 * kk) ^ (brow & 7)) << 3)];
                acc[ct] = __builtin_amdgcn_mfma_f32_16x16x32_bf16(a, b, acc[ct], 0, 0, 0);
            }
        }
        __syncthreads();
    }
    const float qsc = 0.17677669529663687f;   // 1/sqrt(32) folded into q
    #pragma unroll
    for (int ct = 0; ct < 4; ++ct) {
        int col = c0 + ct * 16 + myrow;
        float bval = bias[col];
        #pragma unroll
        for (int r = 0; r < 4; ++r) {
            int tok = t0 + w * 16 + 4 * g + r;
            float vv = acc[ct][r] + bval;
            if (m == 0) vv *= qsc;
            out[tok * Dm + col] = f2bf(vv);
        }
    }
}

// ---------------- v [T][D] -> vT [D][T] transpose (bf16) ----------------
// grid (64, 4), block 256: 64-token x 64-col tiles.
__global__ __launch_bounds__(256)
void transp_v(const ushort* __restrict__ v, ushort* __restrict__ vT)
{
    __shared__ __align__(16) ushort T_s[64 * 72];
    const int tid = threadIdx.x;
    const int t0 = blockIdx.x * 64;
    const int c0 = blockIdx.y * 64;
    #pragma unroll
    for (int s = 0; s < 2; ++s) {
        int idx = s * 256 + tid;
        int row = idx >> 3, c8 = (idx & 7) << 3;
        s16x8 d = *(const s16x8*)&v[(t0 + row) * Dm + c0 + c8];
        #pragma unroll
        for (int j = 0; j < 8; ++j) {
            int c = c8 + j;
            T_s[c * 72 + (row ^ ((c & 7) << 3))] = (ushort)d[j];
        }
    }
    __syncthreads();
    #pragma unroll
    for (int s = 0; s < 2; ++s) {
        int idx = s * 256 + tid;
        int c = idx >> 3, k8 = (idx & 7) << 3;
        s16x8 d = *(const s16x8*)&T_s[c * 72 + (k8 ^ ((c & 7) << 3))];
        *(s16x8*)&vT[(c0 + c) * Tt + t0 + k8] = d;
    }
}

// ---------------- flash attention: direct-global K/V (L2-resident), P via LDS ----------------
// grid 1024 (128 q-tiles x 8 heads), block 256; 4 waves split K 4-ways; combine at end.
__global__ __launch_bounds__(256)
void attn3(const ushort* __restrict__ q, const ushort* __restrict__ kb,
           const ushort* __restrict__ vT, ushort* __restrict__ o)
{
    __shared__ __align__(16) ushort P_s[4][16 * 64];   // per-wave swizzled P (8 KB)
    __shared__ float cmb[96 * 36];                     // combine buffer (13.8 KB)
    const int tid = threadIdx.x;
    const int lane = tid & 63, g = lane >> 4, myrow = lane & 15, w = tid >> 6;
    const int h = blockIdx.x & 7, qt = blockIdx.x >> 3;

    int off, L;
    if (qt < 32)      { off = 0;    L = 1024; }
    else if (qt < 48) { off = 1024; L = 512;  }
    else if (qt < 96) { off = 1536; L = 1536; }
    else              { off = 3072; L = 1024; }
    const int qrow0 = qt * 32;
    const int Lw = L >> 2;
    const int kbeg = off + w * Lw;
    const int ntk = Lw >> 6;

    s16x8 qf[2];
    qf[0] = *(const s16x8*)&q[(qrow0 + myrow) * Dm + h * 32 + g * 8];
    qf[1] = *(const s16x8*)&q[(qrow0 + 16 + myrow) * Dm + h * 32 + g * 8];

    f32x4 aO[2][2] = {};
    float mr[2][4], lr[2][4];
    #pragma unroll
    for (int s = 0; s < 2; ++s)
        #pragma unroll
        for (int r = 0; r < 4; ++r) { mr[s][r] = -INFINITY; lr[s][r] = 0.f; }

    for (int t = 0; t < ntk; ++t) {
        const int kt0 = kbeg + t * 64;
        // K fragments: B-op of QK^T (col=key=myrow, k=dh=8g+j); s-phase invariant.
        s16x8 kf[4];
        #pragma unroll
        for (int kt = 0; kt < 4; ++kt)
            kf[kt] = *(const s16x8*)&kb[(kt0 + kt * 16 + myrow) * Dm + h * 32 + g * 8];
        // V fragments: B-op of PV (col=dh=myrow(+16), k=key=32kk+8g+j); s-phase invariant.
        s16x8 vfa[2], vfb[2];
        #pragma unroll
        for (int kk = 0; kk < 2; ++kk) {
            vfa[kk] = *(const s16x8*)&vT[(h * 32 + myrow) * Tt + kt0 + kk * 32 + g * 8];
            vfb[kk] = *(const s16x8*)&vT[(h * 32 + 16 + myrow) * Tt + kt0 + kk * 32 + g * 8];
        }

        #pragma unroll
        for (int s = 0; s < 2; ++s) {
            const f32x4 zero = {};
            f32x4 s4[4];
            #pragma unroll
            for (int kt = 0; kt < 4; ++kt)
                s4[kt] = __builtin_amdgcn_mfma_f32_16x16x32_bf16(qf[s], kf[kt], zero, 0, 0, 0);

            float mt[4], sc[4], ps[4];
            #pragma unroll
            for (int r = 0; r < 4; ++r) {
                float a = fmaxf(fmaxf(s4[0][r], s4[1][r]), fmaxf(s4[2][r], s4[3][r]));
                a = fmaxf(a, __shfl_xor(a, 1));
                a = fmaxf(a, __shfl_xor(a, 2));
                a = fmaxf(a, __shfl_xor(a, 4));
                a = fmaxf(a, __shfl_xor(a, 8));
                mt[r] = a;
            }
            #pragma unroll
            for (int r = 0; r < 4; ++r) {
                float mn = fmaxf(mr[s][r], mt[r]);
                sc[r] = __expf(mr[s][r] - mn);
                mr[s][r] = mn;
                ps[r] = 0.f;
            }
            // WAR: previous phase's P_s reads must drain before overwrite (wave-local)
            asm volatile("s_waitcnt lgkmcnt(0)" ::: "memory");
            __builtin_amdgcn_sched_barrier(0);
            #pragma unroll
            for (int kt = 0; kt < 4; ++kt) {
                #pragma unroll
                for (int r = 0; r < 4; ++r) {
                    float p = __expf(s4[kt][r] - mr[s][r]);
                    ps[r] += p;
                    P_s[w][ppos(4 * g + r, 16 * kt + myrow)] = f2bf(p);
                }
            }
            #pragma unroll
            for (int r = 0; r < 4; ++r) {
                float sps = ps[r];
                sps += __shfl_xor(sps, 1);
                sps += __shfl_xor(sps, 2);
                sps += __shfl_xor(sps, 4);
                sps += __shfl_xor(sps, 8);
                lr[s][r] = lr[s][r] * sc[r] + sps;
                aO[s][0][r] *= sc[r];
                aO[s][1][r] *= sc[r];
            }
            asm volatile("s_waitcnt lgkmcnt(0)" ::: "memory");  // P writes visible (cross-lane)
            __builtin_amdgcn_sched_barrier(0);
            #pragma unroll
            for (int kk = 0; kk < 2; ++kk) {
                s16x8 ap = *(const s16x8*)&P_s[w][ppos(myrow, (g + 4 * kk) * 8)];
                aO[s][0] = __builtin_amdgcn_mfma_f32_16x16x32_bf16(ap, vfa[kk], aO[s][0], 0, 0, 0);
                aO[s][1] = __builtin_amdgcn_mfma_f32_16x16x32_bf16(ap, vfb[kk], aO[s][1], 0, 0, 0);
            }
        }
    }

    // cross-wave combine: waves 1-3 publish partials, wave 0 merges + writes.
    __syncthreads();
    if (w > 0) {
        #pragma unroll
        for (int s = 0; s < 2; ++s)
            #pragma unroll
            for (int r = 0; r < 4; ++r) {
                int row = (w - 1) * 32 + s * 16 + 4 * g + r;
                cmb[row * 36 + myrow]      = aO[s][0][r];
                cmb[row * 36 + 16 + myrow] = aO[s][1][r];
                if (myrow == 0) { cmb[row * 36 + 32] = mr[s][r]; cmb[row * 36 + 33] = lr[s][r]; }
            }
    }
    __syncthreads();
    if (w == 0) {
        #pragma unroll
        for (int s = 0; s < 2; ++s) {
            #pragma unroll
            for (int r = 0; r < 4; ++r) {
                #pragma unroll
                for (int ww = 0; ww < 3; ++ww) {
                    int row = ww * 32 + s * 16 + 4 * g + r;
                    float m2 = cmb[row * 36 + 32], l2 = cmb[row * 36 + 33];
                    float mn = fmaxf(mr[s][r], m2);
                    float a1 = __expf(mr[s][r] - mn), a2 = __expf(m2 - mn);
                    mr[s][r] = mn;
                    lr[s][r] = lr[s][r] * a1 + l2 * a2;
                    aO[s][0][r] = aO[s][0][r] * a1 + cmb[row * 36 + myrow] * a2;
                    aO[s][1][r] = aO[s][1][r] * a1 + cmb[row * 36 + 16 + myrow] * a2;
                }
                float inv = 1.0f / lr[s][r];
                int orow = (qrow0 + s * 16 + 4 * g + r) * Dm + h * 32;
                o[orow + myrow]      = f2bf(aO[s][0][r] * inv);
                o[orow + 16 + myrow] = f2bf(aO[s][1][r] * inv);
            }
        }
    }
}

// ---------------- output projection ----------------
__global__ __launch_bounds__(256)
void oproj_mfma(const ushort* __restrict__ A, const ushort* __restrict__ Wt3,
                const float* __restrict__ bo, float* __restrict__ out)
{
    __shared__ __align__(16) ushort A_s[32 * 64];
    __shared__ __align__(16) ushort B_s[64 * 64];
    const int tid = threadIdx.x;
    const int lane = tid & 63, g = lane >> 4, myrow = lane & 15, w = tid >> 6;
    const int sh = w >> 1, ch = w & 1;
    const int t0 = blockIdx.x * 32;
    const int c0 = blockIdx.y * 64;

    f32x4 acc[2] = {};
    for (int ks = 0; ks < 4; ++ks) {
        const int k0 = ks * 64;
        {
            int r = tid >> 3, c = tid & 7;
            *(s16x8*)&A_s[r * 64 + ((c ^ (r & 7)) << 3)] =
                *(const s16x8*)&A[(t0 + r) * Dm + k0 + c * 8];
        }
        #pragma unroll
        for (int s = 0; s < 2; ++s) {
            int idx = s * 256 + tid;
            int r = idx >> 3, c = idx & 7;
            *(s16x8*)&B_s[r * 64 + ((c ^ (r & 7)) << 3)] =
                *(const s16x8*)&Wt3[(c0 + r) * Dm + k0 + c * 8];
        }
        __syncthreads();
        const int arow = sh * 16 + myrow;
        #pragma unroll
        for (int kk = 0; kk < 2; ++kk) {
            s16x8 a = *(s16x8*)&A_s[arow * 64 + (((g + 4 * kk) ^ (arow & 7)) << 3)];
            #pragma unroll
            for (int ct = 0; ct < 2; ++ct) {
                int brow = ch * 32 + ct * 16 + myrow;
                s16x8 b = *(s16x8*)&B_s[brow * 64 + (((g + 4 * kk) ^ (brow & 7)) << 3)];
                acc[ct] = __builtin_amdgcn_mfma_f32_16x16x32_bf16(a, b, acc[ct], 0, 0, 0);
            }
        }
        __syncthreads();
    }
    #pragma unroll
    for (int ct = 0; ct < 2; ++ct) {
        int col = c0 + ch * 32 + ct * 16 + myrow;
        float bval = bo[col];
        #pragma unroll
        for (int r = 0; r < 4; ++r)
            out[(t0 + sh * 16 + 4 * g + r) * Dm + col] = acc[ct][r] + bval;
    }
}

extern "C" void kernel_launch(void* const* d_in, const int* in_sizes, int n_in,
                              void* d_out, int out_size, void* d_ws, size_t ws_size,
                              hipStream_t stream) {
    const float* xq  = (const float*)d_in[0];
    const float* xkv = (const float*)d_in[1];
    const float* pos = (const float*)d_in[2];
    const float* Wq  = (const float*)d_in[5];
    const float* bq  = (const float*)d_in[6];
    const float* Wk  = (const float*)d_in[7];
    const float* bk  = (const float*)d_in[8];
    const float* Wv  = (const float*)d_in[9];
    const float* bv  = (const float*)d_in[10];
    const float* Wo  = (const float*)d_in[11];
    const float* bo  = (const float*)d_in[12];

    ushort* Abf = (ushort*)d_ws;           // 3 x [T,D] bf16 (xq+pos, xkv+pos, xkv)
    ushort* qb  = Abf + 3 * Tt * Dm;       // [T,D]
    ushort* kbp = qb + Tt * Dm;            // [T,D]
    ushort* vb  = kbp + Tt * Dm;           // [T,D] row-major v
    ushort* vTt = vb + Tt * Dm;            // [D,T] transposed v
    ushort* ab  = vTt + Tt * Dm;           // attn out [T,D]
    ushort* Wt  = ab + Tt * Dm;            // 4 x [256,256] transposed bf16

    convert_x<<<dim3(Tt / 32, 3), 256, 0, stream>>>(xq, xkv, pos, Abf,
                                                    Abf + Tt * Dm, Abf + 2 * Tt * Dm);
    prep_w<<<dim3(16, 4), 256, 0, stream>>>(Wq, Wk, Wv, Wo, Wt);
    proj_gemm<<<dim3(64, 4, 3), 256, 0, stream>>>(Abf, Abf + Tt * Dm, Abf + 2 * Tt * Dm,
                                                  Wt, bq, bk, bv, qb, kbp, vb);
    transp_v<<<dim3(64, 4), 256, 0, stream>>>(vb, vTt);
    attn3<<<dim3(1024), 256, 0, stream>>>(qb, kbp, vTt, ab);
    oproj_mfma<<<dim3(128, 4), 256, 0, stream>>>(ab, Wt + 3 * 65536, bo, (float*)d_out);
}